// Round 6
// baseline (51.435 us; speedup 1.0000x reference)
//
#include <hip/hip_runtime.h>

// Fused JPEG decompress v5: 256x16-px regions -> every NT store instruction
// writes one fully-contiguous 1-KB row segment.
// Workgroup = 384 threads (6 waves):
//   waves 0..3: Y blocks, wave w = block-row (w>>1), col-half (w&1) (16 blocks)
//   wave 4: 16 Cb blocks, wave 5: 16 Cr blocks (chroma strip 128x8)
// Each lane owns 2 block rows (r and r+4) of one 8x8 block. Stage A in-lane
// (literal cosines); stage B through the wave's private LDS slice; pixels are
// republished into the same slice (safe: DS ops are in-order per wave).
// After one barrier, wave (w>>1) stores plane w>>1, rows (w&1)*8..+7:
// lane l covers px [l*4..l*4+3] of a 256-px row = 1 KB contiguous per instr.

#define IMG_W 1024
#define IMG_HW (1024 * 1024)
#define RSQRT2 0.70710678118654752f

typedef float v4f __attribute__((ext_vector_type(4)));

// COS_LIT[y*8+v] = cos((2v+1)*y*pi/16)  (freq-major; folds to FMA literals)
static constexpr float COS_LIT[64] = {
    1.0f,          1.0f,          1.0f,          1.0f,          1.0f,          1.0f,          1.0f,          1.0f,
    0.980785280f,  0.831469612f,  0.555570233f,  0.195090322f, -0.195090322f, -0.555570233f, -0.831469612f, -0.980785280f,
    0.923879533f,  0.382683432f, -0.382683432f, -0.923879533f, -0.923879533f, -0.382683432f,  0.382683432f,  0.923879533f,
    0.831469612f, -0.195090322f, -0.980785280f, -0.555570233f,  0.555570233f,  0.980785280f,  0.195090322f, -0.831469612f,
    0.707106781f, -0.707106781f, -0.707106781f,  0.707106781f,  0.707106781f, -0.707106781f, -0.707106781f,  0.707106781f,
    0.555570233f, -0.980785280f,  0.195090322f,  0.831469612f, -0.831469612f, -0.195090322f,  0.980785280f, -0.555570233f,
    0.382683432f, -0.923879533f,  0.923879533f, -0.382683432f, -0.382683432f,  0.923879533f, -0.923879533f,  0.382683432f,
    0.195090322f, -0.555570233f,  0.831469612f, -0.980785280f,  0.980785280f, -0.831469612f,  0.555570233f, -0.195090322f};

// COST[u*8+x] = cos((2u+1)*x*pi/16)  (pixel-major; per-lane float4 loads)
__constant__ float COST[64] = {
    1.0f,  0.980785280f,  0.923879533f,  0.831469612f,  0.707106781f,  0.555570233f,  0.382683432f,  0.195090322f,
    1.0f,  0.831469612f,  0.382683432f, -0.195090322f, -0.707106781f, -0.980785280f, -0.923879533f, -0.555570233f,
    1.0f,  0.555570233f, -0.382683432f, -0.980785280f, -0.707106781f,  0.195090322f,  0.923879533f,  0.831469612f,
    1.0f,  0.195090322f, -0.923879533f, -0.555570233f,  0.707106781f,  0.831469612f, -0.382683432f, -0.980785280f,
    1.0f, -0.195090322f, -0.923879533f,  0.555570233f,  0.707106781f, -0.831469612f, -0.382683432f,  0.980785280f,
    1.0f, -0.555570233f, -0.382683432f,  0.980785280f, -0.707106781f, -0.195090322f,  0.923879533f, -0.831469612f,
    1.0f, -0.831469612f,  0.382683432f,  0.195090322f, -0.707106781f,  0.980785280f, -0.923879533f,  0.555570233f,
    1.0f, -0.980785280f,  0.923879533f, -0.831469612f,  0.707106781f, -0.555570233f,  0.382683432f, -0.195090322f};

__constant__ float YTAB[64] = {
    16, 11, 10, 16, 24, 40, 51, 61,
    12, 12, 14, 19, 26, 58, 60, 55,
    14, 13, 16, 24, 40, 57, 69, 56,
    14, 17, 22, 29, 51, 87, 80, 62,
    18, 22, 37, 56, 68, 109, 103, 77,
    24, 35, 55, 64, 81, 104, 113, 92,
    49, 64, 78, 87, 103, 121, 120, 101,
    72, 92, 95, 98, 112, 100, 103, 99};

__constant__ float CTAB[64] = {
    17, 18, 24, 47, 99, 99, 99, 99,
    18, 21, 26, 66, 99, 99, 99, 99,
    24, 26, 56, 99, 99, 99, 99, 99,
    47, 66, 99, 99, 99, 99, 99, 99,
    99, 99, 99, 99, 99, 99, 99, 99,
    99, 99, 99, 99, 99, 99, 99, 99,
    99, 99, 99, 99, 99, 99, 99, 99,
    99, 99, 99, 99, 99, 99, 99, 99};

__global__ __launch_bounds__(384) void jpeg_decode_kernel(
    const float* __restrict__ yq, const float* __restrict__ cbq,
    const float* __restrict__ crq, const float* __restrict__ fac,
    float* __restrict__ out)
{
    // One 8x132-float slice per wave (132 = 128 + 4 skew; 528 B row stride,
    // 16-B aligned). Holds t1 during stage B, then pixels for the store phase.
    __shared__ float sl[6][8][132];

    const int t   = threadIdx.x;
    const int w   = t >> 6;     // wave 0..5
    const int l   = t & 63;
    const int sub = l >> 2;     // block slot 0..15 within wave strip
    const int r   = l & 3;      // low freq-row; lane also owns r+4

    const int gid = blockIdx.x;
    const int rx  = gid & 3;          // region col (256 px each)
    const int ry  = (gid >> 2) & 63;  // region row (16 px each)
    const int img = gid >> 8;

    const float factor = fac[0];

    // ---- loads: each wave reads one 4-KB-contiguous span of ONE array ----
    const float* src;
    const float* qt;
    size_t base;
    if (w < 4) {
        const int br = ry * 2 + (w >> 1);
        const int bc = rx * 32 + (w & 1) * 16 + sub;
        base = ((size_t)(img * 16384 + br * 128 + bc) << 6) + r * 8;
        src = yq;  qt = YTAB;
    } else {
        base = ((size_t)(img * 4096 + ry * 64 + rx * 16 + sub) << 6) + r * 8;
        src = (w == 5) ? crq : cbq;  qt = CTAB;
    }
    const float4 a0  = *reinterpret_cast<const float4*>(src + base);
    const float4 a1  = *reinterpret_cast<const float4*>(src + base + 4);
    const float4 b0  = *reinterpret_cast<const float4*>(src + base + 32);
    const float4 b1  = *reinterpret_cast<const float4*>(src + base + 36);
    const float4 qa0 = *reinterpret_cast<const float4*>(qt + r * 8);
    const float4 qa1 = *reinterpret_cast<const float4*>(qt + r * 8 + 4);
    const float4 qb0 = *reinterpret_cast<const float4*>(qt + (r + 4) * 8);
    const float4 qb1 = *reinterpret_cast<const float4*>(qt + (r + 4) * 8 + 4);

    // ---- dequant: fold 0.25 * alpha_x * alpha_y * factor ----
    const float slo = 0.25f * factor * ((r == 0) ? RSQRT2 : 1.0f);
    const float shi = 0.25f * factor;                 // row r+4 never 0
    float cl[8], ch[8];
    cl[0] = a0.x * (qa0.x * (slo * RSQRT2));
    cl[1] = a0.y * (qa0.y * slo);
    cl[2] = a0.z * (qa0.z * slo);
    cl[3] = a0.w * (qa0.w * slo);
    cl[4] = a1.x * (qa1.x * slo);
    cl[5] = a1.y * (qa1.y * slo);
    cl[6] = a1.z * (qa1.z * slo);
    cl[7] = a1.w * (qa1.w * slo);
    ch[0] = b0.x * (qb0.x * (shi * RSQRT2));
    ch[1] = b0.y * (qb0.y * shi);
    ch[2] = b0.z * (qb0.z * shi);
    ch[3] = b0.w * (qb0.w * shi);
    ch[4] = b1.x * (qb1.x * shi);
    ch[5] = b1.y * (qb1.y * shi);
    ch[6] = b1.z * (qb1.z * shi);
    ch[7] = b1.w * (qb1.w * shi);

    // ---- stage A (in-lane, literal cosines), both rows ----
    float tl[8], th[8];
#pragma unroll
    for (int v = 0; v < 8; ++v) {
        float al = cl[0], ah = ch[0];
#pragma unroll
        for (int y = 1; y < 8; ++y) {
            al += cl[y] * COS_LIT[y * 8 + v];
            ah += ch[y] * COS_LIT[y * 8 + v];
        }
        tl[v] = al;  th[v] = ah;
    }
    const int col0 = sub * 8;
    *reinterpret_cast<float4*>(&sl[w][r][col0])         = make_float4(tl[0], tl[1], tl[2], tl[3]);
    *reinterpret_cast<float4*>(&sl[w][r][col0 + 4])     = make_float4(tl[4], tl[5], tl[6], tl[7]);
    *reinterpret_cast<float4*>(&sl[w][r + 4][col0])     = make_float4(th[0], th[1], th[2], th[3]);
    *reinterpret_cast<float4*>(&sl[w][r + 4][col0 + 4]) = make_float4(th[4], th[5], th[6], th[7]);
    // intra-wave exchange: DS ops are in-order per wave, no barrier needed.

    // ---- stage B: lane = (rr = l>>4, 8-px chunk c8); rows rr and rr+4 ----
    const int rr = l >> 4;
    const int c8 = (l & 15) * 8;
    float cuL[8], cuH[8];
    {
        const float4 u0 = *reinterpret_cast<const float4*>(&COST[rr * 8]);
        const float4 u1 = *reinterpret_cast<const float4*>(&COST[rr * 8 + 4]);
        const float4 v0 = *reinterpret_cast<const float4*>(&COST[(rr + 4) * 8]);
        const float4 v1 = *reinterpret_cast<const float4*>(&COST[(rr + 4) * 8 + 4]);
        cuL[0]=u0.x; cuL[1]=u0.y; cuL[2]=u0.z; cuL[3]=u0.w;
        cuL[4]=u1.x; cuL[5]=u1.y; cuL[6]=u1.z; cuL[7]=u1.w;
        cuH[0]=v0.x; cuH[1]=v0.y; cuH[2]=v0.z; cuH[3]=v0.w;
        cuH[4]=v1.x; cuH[5]=v1.y; cuH[6]=v1.z; cuH[7]=v1.w;
    }
    float pl[8] = {0,0,0,0,0,0,0,0};
    float ph[8] = {0,0,0,0,0,0,0,0};
#pragma unroll
    for (int x = 0; x < 8; ++x) {
        const float4 va = *reinterpret_cast<const float4*>(&sl[w][x][c8]);
        const float4 vb = *reinterpret_cast<const float4*>(&sl[w][x][c8 + 4]);
        pl[0] += cuL[x] * va.x; pl[1] += cuL[x] * va.y; pl[2] += cuL[x] * va.z; pl[3] += cuL[x] * va.w;
        pl[4] += cuL[x] * vb.x; pl[5] += cuL[x] * vb.y; pl[6] += cuL[x] * vb.z; pl[7] += cuL[x] * vb.w;
        ph[0] += cuH[x] * va.x; ph[1] += cuH[x] * va.y; ph[2] += cuH[x] * va.z; ph[3] += cuH[x] * va.w;
        ph[4] += cuH[x] * vb.x; ph[5] += cuH[x] * vb.y; ph[6] += cuH[x] * vb.z; ph[7] += cuH[x] * vb.w;
    }
    // republish pixels over own slice (all t1 reads above precede these writes
    // in wave program order; no +128 — cancels the chroma color shift).
    *reinterpret_cast<float4*>(&sl[w][rr][c8])         = make_float4(pl[0], pl[1], pl[2], pl[3]);
    *reinterpret_cast<float4*>(&sl[w][rr][c8 + 4])     = make_float4(pl[4], pl[5], pl[6], pl[7]);
    *reinterpret_cast<float4*>(&sl[w][rr + 4][c8])     = make_float4(ph[0], ph[1], ph[2], ph[3]);
    *reinterpret_cast<float4*>(&sl[w][rr + 4][c8 + 4]) = make_float4(ph[4], ph[5], ph[6], ph[7]);

    __syncthreads();

    // ---- store phase: wave -> plane (w>>1), rows (w&1)*8 .. +7 ----
    // lane l covers px [l*4 .. l*4+3] of each 256-px row: 1 KB/instr, NT.
    const int plane = w >> 1;
    const int rbase = (w & 1) * 8;
    float* const ob = out + (size_t)img * 3 * IMG_HW + (size_t)plane * IMG_HW
                    + (size_t)(ry * 16) * IMG_W + rx * 256 + l * 4;

#pragma unroll
    for (int s2 = 0; s2 < 8; ++s2) {
        const int rr2 = rbase + s2;
        const int ws  = ((rr2 >> 3) << 1) + (l >> 5);
        const float4 y4 = *reinterpret_cast<const float4*>(&sl[ws][rr2 & 7][(l & 31) * 4]);
        const int crow = rr2 >> 1;
        const float yv[4] = {y4.x + 128.f, y4.y + 128.f, y4.z + 128.f, y4.w + 128.f};
        float o4[4];
        if (plane == 0) {
            const float2 cr2 = *reinterpret_cast<const float2*>(&sl[5][crow][l * 2]);
            o4[0] = yv[0] + 1.402f * cr2.x;
            o4[1] = yv[1] + 1.402f * cr2.x;
            o4[2] = yv[2] + 1.402f * cr2.y;
            o4[3] = yv[3] + 1.402f * cr2.y;
        } else if (plane == 1) {
            const float2 cb2 = *reinterpret_cast<const float2*>(&sl[4][crow][l * 2]);
            const float2 cr2 = *reinterpret_cast<const float2*>(&sl[5][crow][l * 2]);
            o4[0] = yv[0] - 0.344136f * cb2.x - 0.714136f * cr2.x;
            o4[1] = yv[1] - 0.344136f * cb2.x - 0.714136f * cr2.x;
            o4[2] = yv[2] - 0.344136f * cb2.y - 0.714136f * cr2.y;
            o4[3] = yv[3] - 0.344136f * cb2.y - 0.714136f * cr2.y;
        } else {
            const float2 cb2 = *reinterpret_cast<const float2*>(&sl[4][crow][l * 2]);
            o4[0] = yv[0] + 1.772f * cb2.x;
            o4[1] = yv[1] + 1.772f * cb2.x;
            o4[2] = yv[2] + 1.772f * cb2.y;
            o4[3] = yv[3] + 1.772f * cb2.y;
        }
        v4f v;
#pragma unroll
        for (int j = 0; j < 4; ++j)
            v[j] = fminf(fmaxf(o4[j], 0.f), 255.f) * (1.0f / 255.0f);
        __builtin_nontemporal_store(v, reinterpret_cast<v4f*>(ob + (size_t)rr2 * IMG_W));
    }
}

extern "C" void kernel_launch(void* const* d_in, const int* in_sizes, int n_in,
                              void* d_out, int out_size, void* d_ws, size_t ws_size,
                              hipStream_t stream) {
    const float* yq  = (const float*)d_in[0];
    const float* cbq = (const float*)d_in[1];
    const float* crq = (const float*)d_in[2];
    const float* fac = (const float*)d_in[3];
    float* out = (float*)d_out;

    const int B = in_sizes[0] / (16384 * 64);

    dim3 grid(256 * B);                 // 4 x 64 regions per image
    hipLaunchKernelGGL(jpeg_decode_kernel, grid, dim3(384), 0, stream,
                       yq, cbq, crq, fac, out);
}